// Round 3
// 299.608 us; speedup vs baseline: 1.0135x; 1.0135x over previous
//
#include <hip/hip_runtime.h>

typedef unsigned short u16;
typedef short v8s __attribute__((ext_vector_type(8)));   // 8 bf16 in 4 VGPRs
typedef float f4 __attribute__((ext_vector_type(4)));

#define NROWS 262144
#define UNITS 4
// 16384 tiles of 16 rows; unit = (tile, path); 32768 units; 4 units/wave
// -> 8192 waves -> 2048 blocks of 4 waves.

__device__ __forceinline__ u16 f2bf(float f) {
  union { float f; unsigned int i; } x; x.f = f;
  unsigned int r = x.i + 0x7fffu + ((x.i >> 16) & 1u);   // round-nearest-even
  return (u16)(r >> 16);
}

// ---------------------------------------------------------------------------
// Kernel 1: fold M = Wo @ Wv (f32 math -> bf16), c = Wo @ bv + bo (f32),
// copy g/be (f32) into ws. grid 8 x 256 -> 2048 items = mat(2) x n(64) x kg(16)
// ---------------------------------------------------------------------------
__global__ void fuse_weights(const float* __restrict__ Wo1, const float* __restrict__ Wv2,
                             const float* __restrict__ bv2, const float* __restrict__ bo1,
                             const float* __restrict__ Wo2, const float* __restrict__ Wv1,
                             const float* __restrict__ bv1, const float* __restrict__ bo2,
                             const float* __restrict__ g1,  const float* __restrict__ be1,
                             const float* __restrict__ g2,  const float* __restrict__ be2,
                             u16* __restrict__ M1, u16* __restrict__ M2,
                             float* __restrict__ cgb) {
  int item = blockIdx.x * 256 + threadIdx.x;   // 0..2047
  int mat = item >> 10;                        // 0: path1, 1: path2
  int n   = (item >> 4) & 63;                  // output feature (row of M)
  int k0  = (item & 15) * 4;                   // 4 columns per thread
  const float* Wo = mat ? Wo2 : Wo1;
  const float* Wv = mat ? Wv1 : Wv2;
  float a0 = 0.f, a1 = 0.f, a2 = 0.f, a3 = 0.f;
  for (int j = 0; j < 64; ++j) {
    float w = Wo[n * 64 + j];
    f4 wv = *(const f4*)(Wv + j * 64 + k0);
    a0 += w * wv[0];
    a1 += w * wv[1];
    a2 += w * wv[2];
    a3 += w * wv[3];
  }
  u16* M = mat ? M2 : M1;
  M[n * 64 + k0 + 0] = f2bf(a0);
  M[n * 64 + k0 + 1] = f2bf(a1);
  M[n * 64 + k0 + 2] = f2bf(a2);
  M[n * 64 + k0 + 3] = f2bf(a3);
  if ((item & 15) == 0) {
    const float* bv = mat ? bv1 : bv2;
    const float* bo = mat ? bo2 : bo1;
    float s = bo[n];
    for (int j = 0; j < 64; ++j) s += Wo[n * 64 + j] * bv[j];
    cgb[mat * 64 + n] = s;                       // c1 @0, c2 @64
    const float* g  = mat ? g2 : g1;
    const float* be = mat ? be2 : be1;
    cgb[128 + mat * 128 + n] = g[n];             // g1 @128, g2 @256
    cgb[192 + mat * 128 + n] = be[n];            // be1 @192, be2 @320
  }
}

// ---------------------------------------------------------------------------
// Kernel 2: one wave = one (16-row tile, path) x UNITS tiles, software-
// pipelined 1 deep. Per unit: D = M(64x64) @ X^T(64x16) via
// mfma_f32_16x16x32_bf16 (4 M-tiles x 2 K-steps), +c +residual, LN, store.
// Pipeline: [stage(it+1) ... stores(it)] issue order -> the wait before
// compute(it+1) never drains the nt stores; ~8KB of loads stay in flight
// per wave continuously.
// c/g/be live in LDS so their reads ride lgkmcnt, not vmcnt (a global cgb
// read at epilogue would be the newest vmem op and waiting on it would
// force-drain the prefetch).
// bf16 conversion: proven-correct integer RNE (round-0). VALUBusy was 10%,
// so its VALU cost is not on the critical path; cvt_pk asm scrambled the
// B-fragment (round-1 absmax 0.88) and is reverted.
// ---------------------------------------------------------------------------
__global__ __launch_bounds__(256, 3) void xattn(
    const float* __restrict__ v1, const float* __restrict__ v2,
    const u16* __restrict__ M1, const u16* __restrict__ M2,
    const float* __restrict__ cgb,
    float* __restrict__ out1, float* __restrict__ out2) {
  const int lane = threadIdx.x & 63;
  const int wave = threadIdx.x >> 6;
  const int quad = lane >> 4;
  const int l15  = lane & 15;
  const int path = wave & 1;

  __shared__ float scgb[384];
  if (threadIdx.x < 96)
    ((f4*)scgb)[threadIdx.x] = ((const f4*)cgb)[threadIdx.x];

  const u16*   M    = path ? M2  : M1;
  const float* xsrc = path ? v1  : v2;   // matmul input
  const float* rsrc = path ? v2  : v1;   // residual
  float*       outp = path ? out2 : out1;
  const int coff = path * 64;
  const int goff = 128 + path * 128;
  const int boff = 192 + path * 128;

  // Weight A-fragments: A[m = mt*16+l15][k = ks*32+quad*8+j]
  v8s a[4][2];
#pragma unroll
  for (int mt = 0; mt < 4; ++mt)
#pragma unroll
    for (int ks = 0; ks < 2; ++ks)
      a[mt][ks] = *(const v8s*)(M + (mt * 16 + l15) * 64 + ks * 32 + quad * 8);

  const int unit0 = blockIdx.x * 2 + (wave >> 1);   // 0..4095, tile stride 4096

  // double-buffered tile registers
  f4 x0[2], x1[2], x2[2], x3[2];
  f4 rv0[2], rv1[2], rv2[2], rv3[2];

  auto stage = [&](int buf, int tile) {
    const int rr = tile * 16;
    const float* xrow = xsrc + (size_t)(rr + l15) * 64 + quad * 8;
    x0[buf] = *(const f4*)(xrow);
    x1[buf] = *(const f4*)(xrow + 4);
    x2[buf] = *(const f4*)(xrow + 32);
    x3[buf] = *(const f4*)(xrow + 36);
    const float* rrow = rsrc + (size_t)(rr + l15) * 64 + quad * 4;
    rv0[buf] = *(const f4*)(rrow);
    rv1[buf] = *(const f4*)(rrow + 16);
    rv2[buf] = *(const f4*)(rrow + 32);
    rv3[buf] = *(const f4*)(rrow + 48);
  };

  stage(0, unit0);
  __syncthreads();   // cgb visible in LDS; one-time drain

#pragma unroll
  for (int it = 0; it < UNITS; ++it) {
    const int cur = it & 1;
    const int nxt = cur ^ 1;
    const int r0 = (unit0 + it * 4096) * 16;

    // ---- prefetch next tile first (oldest possible issue slot) ----
    if (it + 1 < UNITS) stage(nxt, unit0 + (it + 1) * 4096);

    // ---- convert B-fragment: B[k=quad*8+j][n=l15] = X[r0+l15][k] ----
    v8s b0, b1;
#pragma unroll
    for (int j = 0; j < 4; ++j) {
      b0[j]     = (short)f2bf(x0[cur][j]);
      b0[j + 4] = (short)f2bf(x1[cur][j]);
      b1[j]     = (short)f2bf(x2[cur][j]);
      b1[j + 4] = (short)f2bf(x3[cur][j]);
    }

    f4 acc[4];
#pragma unroll
    for (int mt = 0; mt < 4; ++mt) {
      f4 c = {0.f, 0.f, 0.f, 0.f};
      c = __builtin_amdgcn_mfma_f32_16x16x32_bf16(a[mt][0], b0, c, 0, 0, 0);
      c = __builtin_amdgcn_mfma_f32_16x16x32_bf16(a[mt][1], b1, c, 0, 0, 0);
      acc[mt] = c;
    }

    // ---- +bias +residual, LN stats (acc reused as vals to save VGPRs) ----
    float sum = 0.f, sq = 0.f;
#pragma unroll
    for (int mt = 0; mt < 4; ++mt) {
      const int fo = mt * 16 + quad * 4;
      f4 cf = *(const f4*)(scgb + coff + fo);          // ds_read_b128
      f4 rr = mt == 0 ? rv0[cur] : mt == 1 ? rv1[cur] : mt == 2 ? rv2[cur] : rv3[cur];
#pragma unroll
      for (int j = 0; j < 4; ++j) {
        float t = acc[mt][j] + cf[j] + rr[j];
        acc[mt][j] = t;
        sum += t;
        sq  += t * t;
      }
    }
    // batch row split across lanes {l, l^16, l^32, l^48}: butterfly over quads
    sum += __shfl_xor(sum, 16, 64);
    sq  += __shfl_xor(sq,  16, 64);
    sum += __shfl_xor(sum, 32, 64);
    sq  += __shfl_xor(sq,  32, 64);
    float mean = sum * 0.015625f;
    float var  = sq * 0.015625f - mean * mean;
    float rstd = rsqrtf(var + 1e-5f);

    float* orow = outp + (size_t)(r0 + l15) * 64 + quad * 4;
#pragma unroll
    for (int mt = 0; mt < 4; ++mt) {
      const int fo = mt * 16 + quad * 4;
      f4 g  = *(const f4*)(scgb + goff + fo);          // ds_read_b128
      f4 be = *(const f4*)(scgb + boff + fo);          // ds_read_b128
      f4 o;
#pragma unroll
      for (int j = 0; j < 4; ++j)
        o[j] = (acc[mt][j] - mean) * rstd * g[j] + be[j];
      __builtin_nontemporal_store(o, (f4*)(orow + mt * 16));
    }
  }
}

extern "C" void kernel_launch(void* const* d_in, const int* in_sizes, int n_in,
                              void* d_out, int out_size, void* d_ws, size_t ws_size,
                              hipStream_t stream) {
  const float* v1  = (const float*)d_in[0];
  const float* v2  = (const float*)d_in[1];
  const float* Wv2 = (const float*)d_in[6];
  const float* bv2 = (const float*)d_in[7];
  const float* Wo1 = (const float*)d_in[8];
  const float* bo1 = (const float*)d_in[9];
  const float* Wv1 = (const float*)d_in[14];
  const float* bv1 = (const float*)d_in[15];
  const float* Wo2 = (const float*)d_in[16];
  const float* bo2 = (const float*)d_in[17];
  const float* g1  = (const float*)d_in[18];
  const float* be1 = (const float*)d_in[19];
  const float* g2  = (const float*)d_in[20];
  const float* be2 = (const float*)d_in[21];

  u16* M1 = (u16*)d_ws;                         // 4096 bf16
  u16* M2 = M1 + 4096;                          // 4096 bf16
  float* cgb = (float*)((char*)d_ws + 16384);   // 384 f32: c1,c2,g1,be1,g2,be2

  float* out1 = (float*)d_out;
  float* out2 = out1 + (size_t)NROWS * 64;

  fuse_weights<<<8, 256, 0, stream>>>(Wo1, Wv2, bv2, bo1, Wo2, Wv1, bv1, bo2,
                                      g1, be1, g2, be2, M1, M2, cgb);
  xattn<<<2048, 256, 0, stream>>>(v1, v2, M1, M2, cgb, out1, out2);
}

// Round 5
// 297.579 us; speedup vs baseline: 1.0204x; 1.0068x over previous
//
#include <hip/hip_runtime.h>

typedef unsigned short u16;
typedef short v8s __attribute__((ext_vector_type(8)));   // 8 bf16 in 4 VGPRs
typedef float f4 __attribute__((ext_vector_type(4)));

#define NROWS 262144
#define UNITS 4
// 16384 tiles of 16 rows; unit = (tile, path); 32768 units; 4 units/wave
// -> 8192 waves -> 2048 blocks of 4 waves.

__device__ __forceinline__ u16 f2bf(float f) {
  union { float f; unsigned int i; } x; x.f = f;
  unsigned int r = x.i + 0x7fffu + ((x.i >> 16) & 1u);   // round-nearest-even
  return (u16)(r >> 16);
}

// ---------------------------------------------------------------------------
// Kernel 1: fold M = Wo @ Wv (f32 math -> bf16), c = Wo @ bv + bo (f32),
// copy g/be (f32) into ws. grid 8 x 256 -> 2048 items = mat(2) x n(64) x kg(16)
// ---------------------------------------------------------------------------
__global__ void fuse_weights(const float* __restrict__ Wo1, const float* __restrict__ Wv2,
                             const float* __restrict__ bv2, const float* __restrict__ bo1,
                             const float* __restrict__ Wo2, const float* __restrict__ Wv1,
                             const float* __restrict__ bv1, const float* __restrict__ bo2,
                             const float* __restrict__ g1,  const float* __restrict__ be1,
                             const float* __restrict__ g2,  const float* __restrict__ be2,
                             u16* __restrict__ M1, u16* __restrict__ M2,
                             float* __restrict__ cgb) {
  int item = blockIdx.x * 256 + threadIdx.x;   // 0..2047
  int mat = item >> 10;                        // 0: path1, 1: path2
  int n   = (item >> 4) & 63;                  // output feature (row of M)
  int k0  = (item & 15) * 4;                   // 4 columns per thread
  const float* Wo = mat ? Wo2 : Wo1;
  const float* Wv = mat ? Wv1 : Wv2;
  float a0 = 0.f, a1 = 0.f, a2 = 0.f, a3 = 0.f;
  for (int j = 0; j < 64; ++j) {
    float w = Wo[n * 64 + j];
    f4 wv = *(const f4*)(Wv + j * 64 + k0);
    a0 += w * wv[0];
    a1 += w * wv[1];
    a2 += w * wv[2];
    a3 += w * wv[3];
  }
  u16* M = mat ? M2 : M1;
  M[n * 64 + k0 + 0] = f2bf(a0);
  M[n * 64 + k0 + 1] = f2bf(a1);
  M[n * 64 + k0 + 2] = f2bf(a2);
  M[n * 64 + k0 + 3] = f2bf(a3);
  if ((item & 15) == 0) {
    const float* bv = mat ? bv1 : bv2;
    const float* bo = mat ? bo2 : bo1;
    float s = bo[n];
    for (int j = 0; j < 64; ++j) s += Wo[n * 64 + j] * bv[j];
    cgb[mat * 64 + n] = s;                       // c1 @0, c2 @64
    const float* g  = mat ? g2 : g1;
    const float* be = mat ? be2 : be1;
    cgb[128 + mat * 128 + n] = g[n];             // g1 @128, g2 @256
    cgb[192 + mat * 128 + n] = be[n];            // be1 @192, be2 @320
  }
}

// ---------------------------------------------------------------------------
// Kernel 2: one wave = one (16-row tile, path) x UNITS tiles.
// Per unit: D = M(64x64) @ X^T(64x16) via mfma_f32_16x16x32_bf16
// (4 M-tiles x 2 K-steps), +c +residual, LN, store.
// ROUND-4 CHANGE (single variable vs round 3): nontemporal stores -> plain
// stores. Theory: nt stores bypass L2 and hold per-CU vmem-queue entries for
// ~900cy (HBM ack) instead of ~200cy (L2 ack); with writes = 2/3 of traffic,
// queue occupancy caps chip BW at ~2.6 TB/s (observed). Plain stores ack at
// L2 and let L2 writeback stream to HBM asynchronously. Also expect
// WRITE_SIZE 165 -> ~132 MB (nt partial-line fragmentation removed).
// NOTE round-3 lesson: VGPR_Count=64 proved the register allocator sank the
// explicit double-buffer prefetch (needs >=120 VGPR) -> the sw pipeline never
// materialized; the prefetch code is kept (harmless) but not load-bearing.
// c/g/be live in LDS so their reads ride lgkmcnt, not vmcnt.
// ---------------------------------------------------------------------------
__global__ __launch_bounds__(256, 3) void xattn(
    const float* __restrict__ v1, const float* __restrict__ v2,
    const u16* __restrict__ M1, const u16* __restrict__ M2,
    const float* __restrict__ cgb,
    float* __restrict__ out1, float* __restrict__ out2) {
  const int lane = threadIdx.x & 63;
  const int wave = threadIdx.x >> 6;
  const int quad = lane >> 4;
  const int l15  = lane & 15;
  const int path = wave & 1;

  __shared__ float scgb[384];
  if (threadIdx.x < 96)
    ((f4*)scgb)[threadIdx.x] = ((const f4*)cgb)[threadIdx.x];

  const u16*   M    = path ? M2  : M1;
  const float* xsrc = path ? v1  : v2;   // matmul input
  const float* rsrc = path ? v2  : v1;   // residual
  float*       outp = path ? out2 : out1;
  const int coff = path * 64;
  const int goff = 128 + path * 128;
  const int boff = 192 + path * 128;

  // Weight A-fragments: A[m = mt*16+l15][k = ks*32+quad*8+j]
  v8s a[4][2];
#pragma unroll
  for (int mt = 0; mt < 4; ++mt)
#pragma unroll
    for (int ks = 0; ks < 2; ++ks)
      a[mt][ks] = *(const v8s*)(M + (mt * 16 + l15) * 64 + ks * 32 + quad * 8);

  const int unit0 = blockIdx.x * 2 + (wave >> 1);   // 0..4095, tile stride 4096

  // double-buffered tile registers
  f4 x0[2], x1[2], x2[2], x3[2];
  f4 rv0[2], rv1[2], rv2[2], rv3[2];

  auto stage = [&](int buf, int tile) {
    const int rr = tile * 16;
    const float* xrow = xsrc + (size_t)(rr + l15) * 64 + quad * 8;
    x0[buf] = *(const f4*)(xrow);
    x1[buf] = *(const f4*)(xrow + 4);
    x2[buf] = *(const f4*)(xrow + 32);
    x3[buf] = *(const f4*)(xrow + 36);
    const float* rrow = rsrc + (size_t)(rr + l15) * 64 + quad * 4;
    rv0[buf] = *(const f4*)(rrow);
    rv1[buf] = *(const f4*)(rrow + 16);
    rv2[buf] = *(const f4*)(rrow + 32);
    rv3[buf] = *(const f4*)(rrow + 48);
  };

  stage(0, unit0);
  __syncthreads();   // cgb visible in LDS; one-time drain

#pragma unroll
  for (int it = 0; it < UNITS; ++it) {
    const int cur = it & 1;
    const int nxt = cur ^ 1;
    const int r0 = (unit0 + it * 4096) * 16;

    // ---- prefetch next tile first (oldest possible issue slot) ----
    if (it + 1 < UNITS) stage(nxt, unit0 + (it + 1) * 4096);

    // ---- convert B-fragment: B[k=quad*8+j][n=l15] = X[r0+l15][k] ----
    v8s b0, b1;
#pragma unroll
    for (int j = 0; j < 4; ++j) {
      b0[j]     = (short)f2bf(x0[cur][j]);
      b0[j + 4] = (short)f2bf(x1[cur][j]);
      b1[j]     = (short)f2bf(x2[cur][j]);
      b1[j + 4] = (short)f2bf(x3[cur][j]);
    }

    f4 acc[4];
#pragma unroll
    for (int mt = 0; mt < 4; ++mt) {
      f4 c = {0.f, 0.f, 0.f, 0.f};
      c = __builtin_amdgcn_mfma_f32_16x16x32_bf16(a[mt][0], b0, c, 0, 0, 0);
      c = __builtin_amdgcn_mfma_f32_16x16x32_bf16(a[mt][1], b1, c, 0, 0, 0);
      acc[mt] = c;
    }

    // ---- +bias +residual, LN stats (acc reused as vals to save VGPRs) ----
    float sum = 0.f, sq = 0.f;
#pragma unroll
    for (int mt = 0; mt < 4; ++mt) {
      const int fo = mt * 16 + quad * 4;
      f4 cf = *(const f4*)(scgb + coff + fo);          // ds_read_b128
      f4 rr = mt == 0 ? rv0[cur] : mt == 1 ? rv1[cur] : mt == 2 ? rv2[cur] : rv3[cur];
#pragma unroll
      for (int j = 0; j < 4; ++j) {
        float t = acc[mt][j] + cf[j] + rr[j];
        acc[mt][j] = t;
        sum += t;
        sq  += t * t;
      }
    }
    // batch row split across lanes {l, l^16, l^32, l^48}: butterfly over quads
    sum += __shfl_xor(sum, 16, 64);
    sq  += __shfl_xor(sq,  16, 64);
    sum += __shfl_xor(sum, 32, 64);
    sq  += __shfl_xor(sq,  32, 64);
    float mean = sum * 0.015625f;
    float var  = sq * 0.015625f - mean * mean;
    float rstd = rsqrtf(var + 1e-5f);

    float* orow = outp + (size_t)(r0 + l15) * 64 + quad * 4;
#pragma unroll
    for (int mt = 0; mt < 4; ++mt) {
      const int fo = mt * 16 + quad * 4;
      f4 g  = *(const f4*)(scgb + goff + fo);          // ds_read_b128
      f4 be = *(const f4*)(scgb + boff + fo);          // ds_read_b128
      f4 o;
#pragma unroll
      for (int j = 0; j < 4; ++j)
        o[j] = (acc[mt][j] - mean) * rstd * g[j] + be[j];
      *(f4*)(orow + mt * 16) = o;                      // plain store (ack at L2)
    }
  }
}

extern "C" void kernel_launch(void* const* d_in, const int* in_sizes, int n_in,
                              void* d_out, int out_size, void* d_ws, size_t ws_size,
                              hipStream_t stream) {
  const float* v1  = (const float*)d_in[0];
  const float* v2  = (const float*)d_in[1];
  const float* Wv2 = (const float*)d_in[6];
  const float* bv2 = (const float*)d_in[7];
  const float* Wo1 = (const float*)d_in[8];
  const float* bo1 = (const float*)d_in[9];
  const float* Wv1 = (const float*)d_in[14];
  const float* bv1 = (const float*)d_in[15];
  const float* Wo2 = (const float*)d_in[16];
  const float* bo2 = (const float*)d_in[17];
  const float* g1  = (const float*)d_in[18];
  const float* be1 = (const float*)d_in[19];
  const float* g2  = (const float*)d_in[20];
  const float* be2 = (const float*)d_in[21];

  u16* M1 = (u16*)d_ws;                         // 4096 bf16
  u16* M2 = M1 + 4096;                          // 4096 bf16
  float* cgb = (float*)((char*)d_ws + 16384);   // 384 f32: c1,c2,g1,be1,g2,be2

  float* out1 = (float*)d_out;
  float* out2 = out1 + (size_t)NROWS * 64;

  fuse_weights<<<8, 256, 0, stream>>>(Wo1, Wv2, bv2, bo1, Wo2, Wv1, bv1, bo2,
                                      g1, be1, g2, be2, M1, M2, cgb);
  xattn<<<2048, 256, 0, stream>>>(v1, v2, M1, M2, cgb, out1, out2);
}

// Round 6
// 281.943 us; speedup vs baseline: 1.0770x; 1.0555x over previous
//
#include <hip/hip_runtime.h>

typedef unsigned short u16;
typedef short v8s __attribute__((ext_vector_type(8)));   // 8 bf16 in 4 VGPRs
typedef float f4 __attribute__((ext_vector_type(4)));

#define NROWS 262144
#define UNITS 8
#define TSTRIDE 2048
// 16384 tiles of 16 rows; unit = (tile, path); 32768 units.
// Block = 4 waves; wave owns unit0 = blockIdx*2 + (wave>>1), path = wave&1,
// tiles unit0 + it*2048, it=0..7  -> 1024 blocks.

__device__ __forceinline__ u16 f2bf(float f) {
  union { float f; unsigned int i; } x; x.f = f;
  unsigned int r = x.i + 0x7fffu + ((x.i >> 16) & 1u);   // round-nearest-even
  return (u16)(r >> 16);
}

typedef const __attribute__((address_space(1))) float* gp1;
typedef __attribute__((address_space(3))) float* lp3;
// DMA 64 lanes x 16B -> LDS[base + lane*16]; global addr per-lane.
__device__ __forceinline__ void g2l16(const float* g, float* l) {
  __builtin_amdgcn_global_load_lds((gp1)g, (lp3)l, 16, 0, 0);
}

#define FENCE_LGKM0() asm volatile("s_waitcnt lgkmcnt(0)" ::: "memory")
#define FENCE_VM(n)   asm volatile("s_waitcnt vmcnt(" #n ")" ::: "memory")

// ---------------------------------------------------------------------------
// Kernel 1: fold M = Wo @ Wv (f32 math -> bf16), c = Wo @ bv + bo (f32),
// copy g/be (f32) into ws. grid 8 x 256 -> 2048 items = mat(2) x n(64) x kg(16)
// ---------------------------------------------------------------------------
__global__ void fuse_weights(const float* __restrict__ Wo1, const float* __restrict__ Wv2,
                             const float* __restrict__ bv2, const float* __restrict__ bo1,
                             const float* __restrict__ Wo2, const float* __restrict__ Wv1,
                             const float* __restrict__ bv1, const float* __restrict__ bo2,
                             const float* __restrict__ g1,  const float* __restrict__ be1,
                             const float* __restrict__ g2,  const float* __restrict__ be2,
                             u16* __restrict__ M1, u16* __restrict__ M2,
                             float* __restrict__ cgb) {
  int item = blockIdx.x * 256 + threadIdx.x;   // 0..2047
  int mat = item >> 10;                        // 0: path1, 1: path2
  int n   = (item >> 4) & 63;                  // output feature (row of M)
  int k0  = (item & 15) * 4;                   // 4 columns per thread
  const float* Wo = mat ? Wo2 : Wo1;
  const float* Wv = mat ? Wv1 : Wv2;
  float a0 = 0.f, a1 = 0.f, a2 = 0.f, a3 = 0.f;
  for (int j = 0; j < 64; ++j) {
    float w = Wo[n * 64 + j];
    f4 wv = *(const f4*)(Wv + j * 64 + k0);
    a0 += w * wv[0];
    a1 += w * wv[1];
    a2 += w * wv[2];
    a3 += w * wv[3];
  }
  u16* M = mat ? M2 : M1;
  M[n * 64 + k0 + 0] = f2bf(a0);
  M[n * 64 + k0 + 1] = f2bf(a1);
  M[n * 64 + k0 + 2] = f2bf(a2);
  M[n * 64 + k0 + 3] = f2bf(a3);
  if ((item & 15) == 0) {
    const float* bv = mat ? bv1 : bv2;
    const float* bo = mat ? bo2 : bo1;
    float s = bo[n];
    for (int j = 0; j < 64; ++j) s += Wo[n * 64 + j] * bv[j];
    cgb[mat * 64 + n] = s;                       // c1 @0, c2 @64
    const float* g  = mat ? g2 : g1;
    const float* be = mat ? be2 : be1;
    cgb[128 + mat * 128 + n] = g[n];             // g1 @128, g2 @256
    cgb[192 + mat * 128 + n] = be[n];            // be1 @192, be2 @320
  }
}

// ---------------------------------------------------------------------------
// Kernel 2 (ROUND-6 RESTRUCTURE): allocator-proof LDS-DMA double buffer.
// Round-3/5 lesson: at VGPR=64 the register double-buffer never materialized
// (allocator sank the prefetch); per-CU memory throughput measured ~7 B/cy
// (15% of TA) -> latency-bound from serialized loads, not a throughput wall.
// Fix: global_load_lds DMA (zero VGPRs in flight) into wave-PRIVATE LDS
// (no barriers needed), 1-deep double buffer, counted vmcnt waits pinned by
// asm memory fences. Stores never drained in-loop (vmcnt never 0).
// Staging is full-row contiguous: each DMA = 64 lanes x 16B = 4 rows of 256B.
// vmcnt schedule: prologue stage(u0),stage(u1) -> it0 wait vm(8);
// steady: [lgkm0; stage(it+1); wait vm(12)=prev-stores(4)+next-stage(8)];
// last: wait vm(4). c/g/be in LDS (lgkmcnt path).
// ---------------------------------------------------------------------------
__global__ __launch_bounds__(256, 2) void xattn(
    const float* __restrict__ v1, const float* __restrict__ v2,
    const u16* __restrict__ M1, const u16* __restrict__ M2,
    const float* __restrict__ cgb,
    float* __restrict__ out1, float* __restrict__ out2) {
  const int lane = threadIdx.x & 63;
  const int wave = threadIdx.x >> 6;
  const int quad = lane >> 4;
  const int l15  = lane & 15;
  const int path = wave & 1;

  // [wave][buf][x=0/r=1][16 rows * 64 f32] = 64 KB
  __shared__ float sbuf[4][2][2][1024];
  __shared__ float scgb[384];
  if (threadIdx.x < 96)
    ((f4*)scgb)[threadIdx.x] = ((const f4*)cgb)[threadIdx.x];

  const u16*   M    = path ? M2  : M1;
  const float* xsrc = path ? v1  : v2;   // matmul input
  const float* rsrc = path ? v2  : v1;   // residual
  float*       outp = path ? out2 : out1;
  const int coff = path * 64;
  const int goff = 128 + path * 128;
  const int boff = 192 + path * 128;

  __syncthreads();   // scgb visible; drains prologue vmem before DMA choreography

  // Weight A-fragments: A[m = mt*16+l15][k = ks*32+quad*8+j]
  v8s a[4][2];
#pragma unroll
  for (int mt = 0; mt < 4; ++mt)
#pragma unroll
    for (int ks = 0; ks < 2; ++ks)
      a[mt][ks] = *(const v8s*)(M + (mt * 16 + l15) * 64 + ks * 32 + quad * 8);

  const int unit0 = blockIdx.x * 2 + (wave >> 1);   // 0..2047

  // per-lane source offset within a 4-row DMA group: row lane>>4, col (lane&15)*4
  const int soff = (lane >> 4) * 64 + (lane & 15) * 4;

  // stage one (x,r) 16-row tile into buf via 8 coalesced 1KB DMAs
  auto stage = [&](int buf, int tile) {
    const size_t rbase = (size_t)tile * 16;
    const float* xg = xsrc + rbase * 64 + soff;
    const float* rg = rsrc + rbase * 64 + soff;
    float* xl = &sbuf[wave][buf][0][0];
    float* rl = &sbuf[wave][buf][1][0];
#pragma unroll
    for (int j = 0; j < 4; ++j) {
      g2l16(xg + j * 256, xl + j * 256);   // 4 rows per DMA
      g2l16(rg + j * 256, rl + j * 256);
    }
  };

  stage(0, unit0);                 // buf0 <- unit 0
  stage(1, unit0 + TSTRIDE);       // buf1 <- unit 1

#pragma unroll
  for (int it = 0; it < UNITS; ++it) {
    const int buf = it & 1;

    if (it > 0 && it + 1 < UNITS) {
      FENCE_LGKM0();               // prior-gen ds_reads of this buf retired
      stage(buf ^ 1, unit0 + (it + 1) * TSTRIDE);
    }

    // wait for THIS buf's DMA; never drain stores/next-stage
    if (it == 0)              { FENCE_VM(8); }
    else if (it == UNITS - 1) { FENCE_VM(4); }
    else                      { FENCE_VM(12); }

    const float* xw = &sbuf[wave][buf][0][0];
    const float* rw = &sbuf[wave][buf][1][0];
    f4 x0 = *(const f4*)(xw + l15 * 64 + quad * 8);
    f4 x1 = *(const f4*)(xw + l15 * 64 + quad * 8 + 4);
    f4 x2 = *(const f4*)(xw + l15 * 64 + quad * 8 + 32);
    f4 x3 = *(const f4*)(xw + l15 * 64 + quad * 8 + 36);
    f4 rv[4];
#pragma unroll
    for (int mt = 0; mt < 4; ++mt)
      rv[mt] = *(const f4*)(rw + l15 * 64 + mt * 16 + quad * 4);

    // ---- convert B-fragment: B[k=quad*8+j][n=l15] = X[row l15][k] ----
    v8s b0, b1;
#pragma unroll
    for (int j = 0; j < 4; ++j) {
      b0[j]     = (short)f2bf(x0[j]);
      b0[j + 4] = (short)f2bf(x1[j]);
      b1[j]     = (short)f2bf(x2[j]);
      b1[j + 4] = (short)f2bf(x3[j]);
    }

    f4 acc[4];
#pragma unroll
    for (int mt = 0; mt < 4; ++mt) {
      f4 c = {0.f, 0.f, 0.f, 0.f};
      c = __builtin_amdgcn_mfma_f32_16x16x32_bf16(a[mt][0], b0, c, 0, 0, 0);
      c = __builtin_amdgcn_mfma_f32_16x16x32_bf16(a[mt][1], b1, c, 0, 0, 0);
      acc[mt] = c;
    }

    // ---- +bias +residual, LN stats ----
    float sum = 0.f, sq = 0.f;
#pragma unroll
    for (int mt = 0; mt < 4; ++mt) {
      const int fo = mt * 16 + quad * 4;
      f4 cf = *(const f4*)(scgb + coff + fo);
#pragma unroll
      for (int j = 0; j < 4; ++j) {
        float t = acc[mt][j] + cf[j] + rv[mt][j];
        acc[mt][j] = t;
        sum += t;
        sq  += t * t;
      }
    }
    // batch row split across lanes {l, l^16, l^32, l^48}: butterfly over quads
    sum += __shfl_xor(sum, 16, 64);
    sq  += __shfl_xor(sq,  16, 64);
    sum += __shfl_xor(sum, 32, 64);
    sq  += __shfl_xor(sq,  32, 64);
    float mean = sum * 0.015625f;
    float var  = sq * 0.015625f - mean * mean;
    float rstd = rsqrtf(var + 1e-5f);

    const size_t r0 = (size_t)(unit0 + it * TSTRIDE) * 16;
    float* orow = outp + (r0 + l15) * 64 + quad * 4;
#pragma unroll
    for (int mt = 0; mt < 4; ++mt) {
      const int fo = mt * 16 + quad * 4;
      f4 g  = *(const f4*)(scgb + goff + fo);
      f4 be = *(const f4*)(scgb + boff + fo);
      f4 o;
#pragma unroll
      for (int j = 0; j < 4; ++j)
        o[j] = (acc[mt][j] - mean) * rstd * g[j] + be[j];
      *(f4*)(orow + mt * 16) = o;                      // plain store (L2 ack)
    }
  }
}

extern "C" void kernel_launch(void* const* d_in, const int* in_sizes, int n_in,
                              void* d_out, int out_size, void* d_ws, size_t ws_size,
                              hipStream_t stream) {
  const float* v1  = (const float*)d_in[0];
  const float* v2  = (const float*)d_in[1];
  const float* Wv2 = (const float*)d_in[6];
  const float* bv2 = (const float*)d_in[7];
  const float* Wo1 = (const float*)d_in[8];
  const float* bo1 = (const float*)d_in[9];
  const float* Wv1 = (const float*)d_in[14];
  const float* bv1 = (const float*)d_in[15];
  const float* Wo2 = (const float*)d_in[16];
  const float* bo2 = (const float*)d_in[17];
  const float* g1  = (const float*)d_in[18];
  const float* be1 = (const float*)d_in[19];
  const float* g2  = (const float*)d_in[20];
  const float* be2 = (const float*)d_in[21];

  u16* M1 = (u16*)d_ws;                         // 4096 bf16
  u16* M2 = M1 + 4096;                          // 4096 bf16
  float* cgb = (float*)((char*)d_ws + 16384);   // 384 f32: c1,c2,g1,be1,g2,be2

  float* out1 = (float*)d_out;
  float* out2 = out1 + (size_t)NROWS * 64;

  fuse_weights<<<8, 256, 0, stream>>>(Wo1, Wv2, bv2, bo1, Wo2, Wv1, bv1, bo2,
                                      g1, be1, g2, be2, M1, M2, cgb);
  xattn<<<1024, 256, 0, stream>>>(v1, v2, M1, M2, cgb, out1, out2);
}

// Round 7
// 277.919 us; speedup vs baseline: 1.0926x; 1.0145x over previous
//
#include <hip/hip_runtime.h>

typedef unsigned short u16;
typedef short v8s __attribute__((ext_vector_type(8)));   // 8 bf16 in 4 VGPRs
typedef float f4 __attribute__((ext_vector_type(4)));

#define NROWS 262144
#define UNITS 8
#define TSTRIDE 2048
// 16384 tiles of 16 rows. ROUND-7: one wave owns a tile and computes BOTH
// paths (halves logical read traffic). 2048 waves -> 512 blocks of 4 waves
// = exactly 2 blocks/CU resident. Wave w of block b: tiles b*4+w + it*2048.

__device__ __forceinline__ u16 f2bf(float f) {
  union { float f; unsigned int i; } x; x.f = f;
  unsigned int r = x.i + 0x7fffu + ((x.i >> 16) & 1u);   // round-nearest-even
  return (u16)(r >> 16);
}

typedef const __attribute__((address_space(1))) float* gp1;
typedef __attribute__((address_space(3))) float* lp3;
// DMA 64 lanes x 16B -> LDS[base + lane*16]; global addr per-lane.
__device__ __forceinline__ void g2l16(const float* g, float* l) {
  __builtin_amdgcn_global_load_lds((gp1)g, (lp3)l, 16, 0, 0);
}

#define FENCE_LGKM0() asm volatile("s_waitcnt lgkmcnt(0)" ::: "memory")
#define FENCE_VM(n)   asm volatile("s_waitcnt vmcnt(" #n ")" ::: "memory")

// ---------------------------------------------------------------------------
// Kernel 1: fold M = Wo @ Wv (f32 math -> bf16), c = Wo @ bv + bo (f32),
// copy g/be (f32) into ws. grid 8 x 256 -> 2048 items = mat(2) x n(64) x kg(16)
// ---------------------------------------------------------------------------
__global__ void fuse_weights(const float* __restrict__ Wo1, const float* __restrict__ Wv2,
                             const float* __restrict__ bv2, const float* __restrict__ bo1,
                             const float* __restrict__ Wo2, const float* __restrict__ Wv1,
                             const float* __restrict__ bv1, const float* __restrict__ bo2,
                             const float* __restrict__ g1,  const float* __restrict__ be1,
                             const float* __restrict__ g2,  const float* __restrict__ be2,
                             u16* __restrict__ M1, u16* __restrict__ M2,
                             float* __restrict__ cgb) {
  int item = blockIdx.x * 256 + threadIdx.x;   // 0..2047
  int mat = item >> 10;                        // 0: path1, 1: path2
  int n   = (item >> 4) & 63;                  // output feature (row of M)
  int k0  = (item & 15) * 4;                   // 4 columns per thread
  const float* Wo = mat ? Wo2 : Wo1;
  const float* Wv = mat ? Wv1 : Wv2;
  float a0 = 0.f, a1 = 0.f, a2 = 0.f, a3 = 0.f;
  for (int j = 0; j < 64; ++j) {
    float w = Wo[n * 64 + j];
    f4 wv = *(const f4*)(Wv + j * 64 + k0);
    a0 += w * wv[0];
    a1 += w * wv[1];
    a2 += w * wv[2];
    a3 += w * wv[3];
  }
  u16* M = mat ? M2 : M1;
  M[n * 64 + k0 + 0] = f2bf(a0);
  M[n * 64 + k0 + 1] = f2bf(a1);
  M[n * 64 + k0 + 2] = f2bf(a2);
  M[n * 64 + k0 + 3] = f2bf(a3);
  if ((item & 15) == 0) {
    const float* bv = mat ? bv1 : bv2;
    const float* bo = mat ? bo2 : bo1;
    float s = bo[n];
    for (int j = 0; j < 64; ++j) s += Wo[n * 64 + j] * bv[j];
    cgb[mat * 64 + n] = s;                       // c1 @0, c2 @64
    const float* g  = mat ? g2 : g1;
    const float* be = mat ? be2 : be1;
    cgb[128 + mat * 128 + n] = g[n];             // g1 @128, g2 @256
    cgb[192 + mat * 128 + n] = be[n];            // be1 @192, be2 @320
  }
}

// ---------------------------------------------------------------------------
// Kernel 2 (ROUND-7): merged-path wave + bank-conflict-free LDS.
// Round-6 evidence: fillBuffer memset = 6.6 TB/s on same device (platform cap
// refuted); xattn pinned at 2.5 TB/s HBM but ~5 TB/s at L2 level (each input
// tile was read twice: x by one path-wave, residual by the other); LDS bank
// conflicts 7.34M cy (rows are 256B -> all rows start at bank 0; 16-way).
// Fixes:
//  (1) one wave stages {v1-tile, v2-tile} ONCE via DMA and computes BOTH
//      outputs -> logical reads 268->134 MB, fabric total 402->268 MB.
//  (2) DMA blocks placed at 1040B stride (1KB data + 16B skew): row bank
//      = 4*(row>>2) -> B-frag reads <=2-way (free), residual <=4-way.
// Pipeline unchanged from round 6: wave-private LDS double buffer, DMA
// staging (zero VGPR in flight), counted vmcnt (8 DMAs/stage, 8 stores/unit:
// it0 VM(8), steady VM(16), last VM(8)) -- never drains stores in-loop.
// ---------------------------------------------------------------------------
__global__ __launch_bounds__(256, 2) void xattn(
    const float* __restrict__ v1, const float* __restrict__ v2,
    const u16* __restrict__ M1, const u16* __restrict__ M2,
    const float* __restrict__ cgb,
    float* __restrict__ out1, float* __restrict__ out2) {
  const int lane = threadIdx.x & 63;
  const int wave = threadIdx.x >> 6;
  const int quad = lane >> 4;
  const int l15  = lane & 15;

  // [wave][buf][v1=0/v2=1][4 blocks x 260 dwords] ; block = 4 rows x 64 f32
  __shared__ float sbuf[4][2][2][1040];
  __shared__ float scgb[384];
  if (threadIdx.x < 96)
    ((f4*)scgb)[threadIdx.x] = ((const f4*)cgb)[threadIdx.x];
  __syncthreads();   // scgb visible (also drains its global reads)

  // Weight A-fragments for BOTH paths: A[m = mt*16+l15][k = ks*32+quad*8+j]
  v8s a1[4][2], a2[4][2];
#pragma unroll
  for (int mt = 0; mt < 4; ++mt)
#pragma unroll
    for (int ks = 0; ks < 2; ++ks) {
      a1[mt][ks] = *(const v8s*)(M1 + (mt * 16 + l15) * 64 + ks * 32 + quad * 8);
      a2[mt][ks] = *(const v8s*)(M2 + (mt * 16 + l15) * 64 + ks * 32 + quad * 8);
    }

  const int t0 = blockIdx.x * 4 + wave;            // 0..2047
  // padded row offset inside a tile buffer (dwords)
  const int ro = (l15 >> 2) * 260 + (l15 & 3) * 64;

  auto stage = [&](int buf, int tile) {
    const float* gp1v = v1 + (size_t)tile * 1024 + lane * 4;
    const float* gp2v = v2 + (size_t)tile * 1024 + lane * 4;
    float* l1 = &sbuf[wave][buf][0][0];
    float* l2 = &sbuf[wave][buf][1][0];
#pragma unroll
    for (int j = 0; j < 4; ++j) {
      g2l16(gp1v + j * 256, l1 + j * 260);   // 4 rows (1KB) per DMA, 1040B skewed
      g2l16(gp2v + j * 256, l2 + j * 260);
    }
  };

  stage(0, t0);                 // buf0 <- unit 0
  stage(1, t0 + TSTRIDE);       // buf1 <- unit 1

  // one path: out = LN(M @ bf16(xw) + c + rw), xw/rw are LDS tile pointers
  auto dopath = [&](const v8s (&am)[4][2], const float* xw, const float* rw,
                    int coff, int goff, int boff, float* outp, size_t r0) {
    f4 x0 = *(const f4*)(xw + ro + quad * 8);
    f4 x1 = *(const f4*)(xw + ro + quad * 8 + 4);
    f4 x2 = *(const f4*)(xw + ro + quad * 8 + 32);
    f4 x3 = *(const f4*)(xw + ro + quad * 8 + 36);
    f4 rv[4];
#pragma unroll
    for (int mt = 0; mt < 4; ++mt)
      rv[mt] = *(const f4*)(rw + ro + mt * 16 + quad * 4);

    v8s b0, b1;
#pragma unroll
    for (int j = 0; j < 4; ++j) {
      b0[j]     = (short)f2bf(x0[j]);
      b0[j + 4] = (short)f2bf(x1[j]);
      b1[j]     = (short)f2bf(x2[j]);
      b1[j + 4] = (short)f2bf(x3[j]);
    }

    f4 acc[4];
#pragma unroll
    for (int mt = 0; mt < 4; ++mt) {
      f4 c = {0.f, 0.f, 0.f, 0.f};
      c = __builtin_amdgcn_mfma_f32_16x16x32_bf16(am[mt][0], b0, c, 0, 0, 0);
      c = __builtin_amdgcn_mfma_f32_16x16x32_bf16(am[mt][1], b1, c, 0, 0, 0);
      acc[mt] = c;
    }

    float sum = 0.f, sq = 0.f;
#pragma unroll
    for (int mt = 0; mt < 4; ++mt) {
      const int fo = mt * 16 + quad * 4;
      f4 cf = *(const f4*)(scgb + coff + fo);
#pragma unroll
      for (int j = 0; j < 4; ++j) {
        float t = acc[mt][j] + cf[j] + rv[mt][j];
        acc[mt][j] = t;
        sum += t;
        sq  += t * t;
      }
    }
    sum += __shfl_xor(sum, 16, 64);
    sq  += __shfl_xor(sq,  16, 64);
    sum += __shfl_xor(sum, 32, 64);
    sq  += __shfl_xor(sq,  32, 64);
    float mean = sum * 0.015625f;
    float var  = sq * 0.015625f - mean * mean;
    float rstd = rsqrtf(var + 1e-5f);

    float* orow = outp + (r0 + l15) * 64 + quad * 4;
#pragma unroll
    for (int mt = 0; mt < 4; ++mt) {
      const int fo = mt * 16 + quad * 4;
      f4 g  = *(const f4*)(scgb + goff + fo);
      f4 be = *(const f4*)(scgb + boff + fo);
      f4 o;
#pragma unroll
      for (int j = 0; j < 4; ++j)
        o[j] = (acc[mt][j] - mean) * rstd * g[j] + be[j];
      *(f4*)(orow + mt * 16) = o;                      // plain store (L2 ack)
    }
  };

#pragma unroll
  for (int it = 0; it < UNITS; ++it) {
    const int buf = it & 1;

    if (it > 0 && it + 1 < UNITS) {
      FENCE_LGKM0();               // prior-gen ds_reads of the buf being overwritten
      stage(buf ^ 1, t0 + (it + 1) * TSTRIDE);
    }

    // wait for THIS buf's 8 DMAs; stores/next-stage stay in flight
    if (it == 0 || it == UNITS - 1) { FENCE_VM(8); }
    else                            { FENCE_VM(16); }

    const float* w1 = &sbuf[wave][buf][0][0];   // v1 tile
    const float* w2 = &sbuf[wave][buf][1][0];   // v2 tile
    const size_t r0 = (size_t)(t0 + it * TSTRIDE) * 16;

    // path0 -> out1: x = v2, residual = v1 ; path1 -> out2: x = v1, residual = v2
    dopath(a1, w2, w1, 0, 128, 192, out1, r0);
    dopath(a2, w1, w2, 64, 256, 320, out2, r0);
  }
}

extern "C" void kernel_launch(void* const* d_in, const int* in_sizes, int n_in,
                              void* d_out, int out_size, void* d_ws, size_t ws_size,
                              hipStream_t stream) {
  const float* v1  = (const float*)d_in[0];
  const float* v2  = (const float*)d_in[1];
  const float* Wv2 = (const float*)d_in[6];
  const float* bv2 = (const float*)d_in[7];
  const float* Wo1 = (const float*)d_in[8];
  const float* bo1 = (const float*)d_in[9];
  const float* Wv1 = (const float*)d_in[14];
  const float* bv1 = (const float*)d_in[15];
  const float* Wo2 = (const float*)d_in[16];
  const float* bo2 = (const float*)d_in[17];
  const float* g1  = (const float*)d_in[18];
  const float* be1 = (const float*)d_in[19];
  const float* g2  = (const float*)d_in[20];
  const float* be2 = (const float*)d_in[21];

  u16* M1 = (u16*)d_ws;                         // 4096 bf16
  u16* M2 = M1 + 4096;                          // 4096 bf16
  float* cgb = (float*)((char*)d_ws + 16384);   // 384 f32: c1,c2,g1,be1,g2,be2

  float* out1 = (float*)d_out;
  float* out2 = out1 + (size_t)NROWS * 64;

  fuse_weights<<<8, 256, 0, stream>>>(Wo1, Wv2, bv2, bo1, Wo2, Wv1, bv1, bo2,
                                      g1, be1, g2, be2, M1, M2, cgb);
  xattn<<<512, 256, 0, stream>>>(v1, v2, M1, M2, cgb, out1, out2);
}